// Round 3
// baseline (1136.267 us; speedup 1.0000x reference)
//
#include <hip/hip_runtime.h>
#include <cstdint>
#include <cstddef>

#define B_ 2
#define N_ 2048
#define C_ 1024
#define H_ 16

typedef unsigned short u16;
typedef __attribute__((ext_vector_type(8))) short bf16x8;   // MFMA A/B frag: 8 bf16 (4 VGPR)
typedef __attribute__((ext_vector_type(4))) float f32x4;    // MFMA C/D frag
typedef __attribute__((ext_vector_type(8))) u16 u16x8;
typedef __attribute__((ext_vector_type(4))) u16 u16x4;

static __device__ __forceinline__ u16 f2bf(float f) {
  unsigned int u = __builtin_bit_cast(unsigned int, f);
  u += 0x7FFFu + ((u >> 16) & 1u);   // RNE
  return (u16)(u >> 16);
}
static __device__ __forceinline__ float bf2f(u16 h) {
  unsigned int u = ((unsigned int)h) << 16;
  return __builtin_bit_cast(float, u);
}

// ---------------------------------------------------------------------------
// elementwise fp32 -> bf16 (exact-size grid, 4 elems/thread)
// ---------------------------------------------------------------------------
__global__ void cvt_f32_bf16(const float* __restrict__ in, u16* __restrict__ out) {
  const size_t i = (size_t)(blockIdx.x * blockDim.x + threadIdx.x) * 4;
  const float4 v = *(const float4*)(in + i);
  u16x4 o;
  o[0] = f2bf(v.x); o[1] = f2bf(v.y); o[2] = f2bf(v.z); o[3] = f2bf(v.w);
  *(u16x4*)(out + i) = o;
}

// ---------------------------------------------------------------------------
// transpose + convert: in fp32 [R][Cn] -> out bf16 [Cn][R].  32x32 LDS tile.
// ---------------------------------------------------------------------------
__global__ void tcvt_bf16(const float* __restrict__ in, u16* __restrict__ out,
                          int R, int Cn) {
  __shared__ float T[32][33];
  const int t = threadIdx.x;
  const int c0 = blockIdx.x * 32, r0 = blockIdx.y * 32;
  {
    const int r = t >> 3, c4 = (t & 7) * 4;
    const float4 v = *(const float4*)(in + (size_t)(r0 + r) * Cn + c0 + c4);
    T[r][c4 + 0] = v.x; T[r][c4 + 1] = v.y; T[r][c4 + 2] = v.z; T[r][c4 + 3] = v.w;
  }
  __syncthreads();
  {
    const int c = t >> 3, r4 = (t & 7) * 4;
    u16x4 o;
    o[0] = f2bf(T[r4 + 0][c]); o[1] = f2bf(T[r4 + 1][c]);
    o[2] = f2bf(T[r4 + 2][c]); o[3] = f2bf(T[r4 + 3][c]);
    *(u16x4*)(out + (size_t)(c0 + c) * R + r0 + r4) = o;
  }
}

// ---------------------------------------------------------------------------
// bf16 MFMA GEMM: C[M,Nn] = A[M,K] @ B[K,Nn], A row-major bf16, Bt = B^T
// row-major bf16 ([Nn][K]).  128x128 tile, BK=32, 256 threads = 4 waves (2x2),
// each wave 64x64 = 4x4 frags of 16x16x32.  Out: fp32+bias or bf16.
// LDS stride 40 bf16 = 80 B: 16B-aligned b128 reads, <=2-way banks (free).
// ---------------------------------------------------------------------------
template<bool BIAS, bool OUTBF>
__global__ __launch_bounds__(256, 2)
void gemm_bf16(const u16* __restrict__ A, const u16* __restrict__ Bt,
               const float* __restrict__ bias, float* __restrict__ Cf,
               u16* __restrict__ Cb, int M, int Nn, int K)
{
  __shared__ u16 As[128][40];
  __shared__ u16 Bs[128][40];

  const int tid = threadIdx.x;
  const int lane = tid & 63, wv = tid >> 6;
  const int wr = wv >> 1, wc = wv & 1;
  const int lr = lane & 15, lk = (lane >> 4) * 8;

  f32x4 acc[4][4];
#pragma unroll
  for (int m = 0; m < 4; ++m)
#pragma unroll
    for (int n = 0; n < 4; ++n) acc[m][n] = (f32x4){0.f, 0.f, 0.f, 0.f};

  const u16* Ag = A + (size_t)(blockIdx.y * 128) * K;
  const u16* Bg = Bt + (size_t)(blockIdx.x * 128) * K;

  for (int kt = 0; kt < K; kt += 32) {
    // stage 128x32 bf16 tiles of A and B^T (both contiguous-K row-major)
#pragma unroll
    for (int i = 0; i < 2; ++i) {
      const int f = tid + i * 256;
      const int row = f >> 2, kq = (f & 3) * 8;
      *(u16x8*)&As[row][kq] = *(const u16x8*)(Ag + (size_t)row * K + kt + kq);
      *(u16x8*)&Bs[row][kq] = *(const u16x8*)(Bg + (size_t)row * K + kt + kq);
    }
    __syncthreads();

    bf16x8 a[4], b[4];
#pragma unroll
    for (int m = 0; m < 4; ++m) a[m] = *(bf16x8*)&As[wr * 64 + m * 16 + lr][lk];
#pragma unroll
    for (int n = 0; n < 4; ++n) b[n] = *(bf16x8*)&Bs[wc * 64 + n * 16 + lr][lk];
#pragma unroll
    for (int m = 0; m < 4; ++m)
#pragma unroll
      for (int n = 0; n < 4; ++n)
        acc[m][n] = __builtin_amdgcn_mfma_f32_16x16x32_bf16(a[m], b[n], acc[m][n], 0, 0, 0);
    __syncthreads();
  }

  // epilogue: C/D layout col=lane&15, row=(lane>>4)*4+reg   [m89/m91]
#pragma unroll
  for (int n = 0; n < 4; ++n) {
    const int col = blockIdx.x * 128 + wc * 64 + n * 16 + lr;
    const float bv = BIAS ? bias[col] : 0.f;
#pragma unroll
    for (int m = 0; m < 4; ++m) {
      const int rbase = blockIdx.y * 128 + wr * 64 + m * 16 + (lane >> 4) * 4;
#pragma unroll
      for (int r = 0; r < 4; ++r) {
        if (OUTBF) Cb[(size_t)(rbase + r) * Nn + col] = f2bf(acc[m][n][r]);
        else       Cf[(size_t)(rbase + r) * Nn + col] = acc[m][n][r] + bv;
      }
    }
  }
}

// ---------------------------------------------------------------------------
// Flash attention, bf16 in (qkv [B,N,3,H,D] bf16) / bf16 out, fp32 compute.
// Block = 256 = 64 q-rows x 4 col-segs.  Grid (N/64, B*H).
// ---------------------------------------------------------------------------
__global__ __launch_bounds__(256, 2)
void attn_bf16(const u16* __restrict__ qkv, u16* __restrict__ att)
{
  __shared__ float Ps[64][65];
  __shared__ float Kt[64][68];
  __shared__ float Vs[64][68];
  __shared__ float pmax[4][64];
  __shared__ float psum[4][64];

  const int tid = threadIdx.x;
  const int r   = tid & 63;
  const int seg = tid >> 6;
  const int qt = blockIdx.x;
  const int bh = blockIdx.y;
  const int b = bh >> 4, h = bh & 15;

  const size_t base = (size_t)b * N_ * 3072 + (size_t)h * 64;

  // stage Q (64x64 bf16), pull own row to regs
#pragma unroll
  for (int i = 0; i < 2; ++i) {
    const int f = tid + i * 256;
    const int row = f >> 3, d8 = (f & 7) * 8;
    const u16x8 v = *(const u16x8*)(qkv + base + (size_t)(qt * 64 + row) * 3072 + d8);
#pragma unroll
    for (int j = 0; j < 8; ++j) Ps[row][d8 + j] = bf2f(v[j]);
  }
  __syncthreads();
  float q[64];
#pragma unroll
  for (int k = 0; k < 64; ++k) q[k] = Ps[r][k] * 0.125f;  // 1/sqrt(64)
  __syncthreads();

  float o[16];
#pragma unroll
  for (int i = 0; i < 16; ++i) o[i] = 0.f;
  float m = -INFINITY, l = 0.f;

  for (int t = 0; t < N_ / 64; ++t) {
    // stage K (transposed) and V
#pragma unroll
    for (int i = 0; i < 2; ++i) {
      const int f = tid + i * 256;
      const int row = f >> 3, d8 = (f & 7) * 8;
      const u16x8 kv = *(const u16x8*)(qkv + base + 1024 + (size_t)(t * 64 + row) * 3072 + d8);
#pragma unroll
      for (int j = 0; j < 8; ++j) Kt[d8 + j][row] = bf2f(kv[j]);
      const u16x8 vv = *(const u16x8*)(qkv + base + 2048 + (size_t)(t * 64 + row) * 3072 + d8);
      float4 w0, w1;
      w0.x = bf2f(vv[0]); w0.y = bf2f(vv[1]); w0.z = bf2f(vv[2]); w0.w = bf2f(vv[3]);
      w1.x = bf2f(vv[4]); w1.y = bf2f(vv[5]); w1.z = bf2f(vv[6]); w1.w = bf2f(vv[7]);
      *(float4*)&Vs[row][d8] = w0;
      *(float4*)&Vs[row][d8 + 4] = w1;
    }
    __syncthreads();

    // scores for cols seg*16 .. +15
    float s[16];
#pragma unroll
    for (int j = 0; j < 16; ++j) s[j] = 0.f;
#pragma unroll
    for (int k = 0; k < 64; ++k) {
      const float qv = q[k];
#pragma unroll
      for (int g = 0; g < 4; ++g) {
        const float4 kk = *(const float4*)&Kt[k][seg * 16 + g * 4];  // wave-uniform bcast
        s[g * 4 + 0] += qv * kk.x;
        s[g * 4 + 1] += qv * kk.y;
        s[g * 4 + 2] += qv * kk.z;
        s[g * 4 + 3] += qv * kk.w;
      }
    }

    // online softmax
    float pm = s[0];
#pragma unroll
    for (int j = 1; j < 16; ++j) pm = fmaxf(pm, s[j]);
    pmax[seg][r] = pm;
    __syncthreads();
    const float mnew = fmaxf(fmaxf(fmaxf(pmax[0][r], pmax[1][r]),
                                   fmaxf(pmax[2][r], pmax[3][r])), m);
    const float sc = __expf(m - mnew);
    m = mnew;
    float ps = 0.f;
#pragma unroll
    for (int j = 0; j < 16; ++j) {
      s[j] = __expf(s[j] - mnew);
      ps += s[j];
    }
#pragma unroll
    for (int j = 0; j < 16; ++j) Ps[r][seg * 16 + j] = s[j];
    psum[seg][r] = ps;
    __syncthreads();
    l = l * sc + psum[0][r] + psum[1][r] + psum[2][r] + psum[3][r];
#pragma unroll
    for (int i = 0; i < 16; ++i) o[i] *= sc;

    // O += P @ V
#pragma unroll
    for (int j = 0; j < 64; ++j) {
      const float p = Ps[r][j];
#pragma unroll
      for (int g = 0; g < 4; ++g) {
        const float4 vv = *(const float4*)&Vs[j][seg * 16 + g * 4];  // wave-uniform bcast
        o[g * 4 + 0] += p * vv.x;
        o[g * 4 + 1] += p * vv.y;
        o[g * 4 + 2] += p * vv.z;
        o[g * 4 + 3] += p * vv.w;
      }
    }
    __syncthreads();
  }

  const float inv = 1.f / l;
  u16* dst = att + (size_t)(b * N_ + qt * 64 + r) * C_ + h * 64 + seg * 16;
#pragma unroll
  for (int g = 0; g < 4; ++g) {
    u16x4 ov;
    ov[0] = f2bf(o[g * 4 + 0] * inv);
    ov[1] = f2bf(o[g * 4 + 1] * inv);
    ov[2] = f2bf(o[g * 4 + 2] * inv);
    ov[3] = f2bf(o[g * 4 + 3] * inv);
    *(u16x4*)(dst + g * 4) = ov;
  }
}

// ---------------------------------------------------------------------------
extern "C" void kernel_launch(void* const* d_in, const int* in_sizes, int n_in,
                              void* d_out, int out_size, void* d_ws, size_t ws_size,
                              hipStream_t stream) {
  const float* x      = (const float*)d_in[0];   // [B, N, C]
  const float* w_qkv  = (const float*)d_in[1];   // [C, 3C]
  const float* w_proj = (const float*)d_in[2];   // [C, C]
  const float* b_proj = (const float*)d_in[3];   // [C]
  float* out = (float*)d_out;                    // [B, N, C] fp32

  // ws layout (48 MB total, all bf16):
  u16* qkvb = (u16*)d_ws;                        // [4096][3072]
  u16* xb   = qkvb + (size_t)4096 * 3072;        // [4096][1024]
  u16* wqt  = xb   + (size_t)4096 * 1024;        // [3072][1024] = w_qkv^T
  u16* wpt  = wqt  + (size_t)3072 * 1024;        // [1024][1024] = w_proj^T
  u16* aob  = wpt  + (size_t)1024 * 1024;        // [4096][1024]

  const int M = B_ * N_;  // 4096

  // converters
  cvt_f32_bf16<<<4096, 256, 0, stream>>>(x, xb);                       // 4M elems
  tcvt_bf16<<<dim3(96, 32), 256, 0, stream>>>(w_qkv, wqt, C_, 3 * C_);
  tcvt_bf16<<<dim3(32, 32), 256, 0, stream>>>(w_proj, wpt, C_, C_);

  // 1) QKV projection: [4096,1024] @ [1024,3072] -> bf16 qkv
  gemm_bf16<false, true><<<dim3(3 * C_ / 128, M / 128), 256, 0, stream>>>(
      xb, wqt, nullptr, nullptr, qkvb, M, 3 * C_, C_);

  // 2) attention (bf16 io, fp32 compute)
  attn_bf16<<<dim3(N_ / 64, B_ * H_), 256, 0, stream>>>(qkvb, aob);

  // 3) output projection + bias -> fp32 d_out
  gemm_bf16<true, false><<<dim3(C_ / 128, M / 128), 256, 0, stream>>>(
      aob, wpt, b_proj, out, nullptr, M, C_, C_);
}

// Round 7
// 277.164 us; speedup vs baseline: 4.0996x; 4.0996x over previous
//
#include <hip/hip_runtime.h>
#include <cstdint>
#include <cstddef>

#define B_ 2
#define N_ 2048
#define C_ 1024
#define H_ 16

typedef unsigned short u16;
typedef __attribute__((ext_vector_type(8))) short bf16x8;   // MFMA A/B frag: 8 bf16 (4 VGPR)
typedef __attribute__((ext_vector_type(4))) float f32x4;    // MFMA C/D frag
typedef __attribute__((ext_vector_type(8))) u16 u16x8;
typedef __attribute__((ext_vector_type(4))) u16 u16x4;

static __device__ __forceinline__ u16 f2bf(float f) {
  unsigned int u = __builtin_bit_cast(unsigned int, f);
  u += 0x7FFFu + ((u >> 16) & 1u);   // RNE
  return (u16)(u >> 16);
}

// ---------------------------------------------------------------------------
// elementwise fp32 -> bf16 (exact-size grid, 4 elems/thread)
// ---------------------------------------------------------------------------
__global__ void cvt_f32_bf16(const float* __restrict__ in, u16* __restrict__ out) {
  const size_t i = (size_t)(blockIdx.x * blockDim.x + threadIdx.x) * 4;
  const float4 v = *(const float4*)(in + i);
  u16x4 o;
  o[0] = f2bf(v.x); o[1] = f2bf(v.y); o[2] = f2bf(v.z); o[3] = f2bf(v.w);
  *(u16x4*)(out + i) = o;
}

// ---------------------------------------------------------------------------
// transpose + convert: in fp32 [R][Cn] -> out bf16 [Cn][R].  32x32 LDS tile.
// ---------------------------------------------------------------------------
__global__ void tcvt_bf16(const float* __restrict__ in, u16* __restrict__ out,
                          int R, int Cn) {
  __shared__ float T[32][33];
  const int t = threadIdx.x;
  const int c0 = blockIdx.x * 32, r0 = blockIdx.y * 32;
  {
    const int r = t >> 3, c4 = (t & 7) * 4;
    const float4 v = *(const float4*)(in + (size_t)(r0 + r) * Cn + c0 + c4);
    T[r][c4 + 0] = v.x; T[r][c4 + 1] = v.y; T[r][c4 + 2] = v.z; T[r][c4 + 3] = v.w;
  }
  __syncthreads();
  {
    const int c = t >> 3, r4 = (t & 7) * 4;
    u16x4 o;
    o[0] = f2bf(T[r4 + 0][c]); o[1] = f2bf(T[r4 + 1][c]);
    o[2] = f2bf(T[r4 + 2][c]); o[3] = f2bf(T[r4 + 3][c]);
    *(u16x4*)(out + (size_t)(c0 + c) * R + r0 + r4) = o;
  }
}

// ---------------------------------------------------------------------------
// V transpose: qkv [B,N,3,H,D] bf16 V-part -> vt [(b*16+h)*64+d][N] bf16.
// One block per (bh, 64-token tile); 64x64 LDS tile, stride 72 (conflict-free).
// ---------------------------------------------------------------------------
__global__ __launch_bounds__(256, 4)
void vtrans(const u16* __restrict__ qkv, u16* __restrict__ vt) {
  __shared__ u16 T[64][72];
  const int tid = threadIdx.x;
  const int bh = blockIdx.x, tile = blockIdx.y;
  const int b = bh >> 4, h = bh & 15;
  const size_t src = (size_t)(b * N_ + tile * 64) * 3072 + 2048 + h * 64;
#pragma unroll
  for (int i = 0; i < 2; ++i) {
    const int f = tid + i * 256;
    const int row = f >> 3, d8 = (f & 7) * 8;
    *(u16x8*)&T[row][d8] = *(const u16x8*)(qkv + src + (size_t)row * 3072 + d8);
  }
  __syncthreads();
#pragma unroll
  for (int i = 0; i < 2; ++i) {
    const int f = tid + i * 256;
    const int d = f >> 3, n8 = (f & 7) * 8;
    u16x8 o;
#pragma unroll
    for (int j = 0; j < 8; ++j) o[j] = T[n8 + j][d];
    *(u16x8*)(vt + (size_t)(bh * 64 + d) * N_ + tile * 64 + n8) = o;
  }
}

// ---------------------------------------------------------------------------
// bf16 MFMA GEMM: C[M,Nn] = A[M,K] @ B[K,Nn], A row-major bf16, Bt = B^T
// row-major bf16 ([Nn][K]).  128x128 tile, BK=32, 4 waves (2x2), 4x4 frags.
// ---------------------------------------------------------------------------
template<bool BIAS, bool OUTBF>
__global__ __launch_bounds__(256, 2)
void gemm_bf16(const u16* __restrict__ A, const u16* __restrict__ Bt,
               const float* __restrict__ bias, float* __restrict__ Cf,
               u16* __restrict__ Cb, int M, int Nn, int K)
{
  __shared__ u16 As[128][40];
  __shared__ u16 Bs[128][40];

  const int tid = threadIdx.x;
  const int lane = tid & 63, wv = tid >> 6;
  const int wr = wv >> 1, wc = wv & 1;
  const int lr = lane & 15, lk = (lane >> 4) * 8;

  f32x4 acc[4][4];
#pragma unroll
  for (int m = 0; m < 4; ++m)
#pragma unroll
    for (int n = 0; n < 4; ++n) acc[m][n] = (f32x4){0.f, 0.f, 0.f, 0.f};

  const u16* Ag = A + (size_t)(blockIdx.y * 128) * K;
  const u16* Bg = Bt + (size_t)(blockIdx.x * 128) * K;

  for (int kt = 0; kt < K; kt += 32) {
#pragma unroll
    for (int i = 0; i < 2; ++i) {
      const int f = tid + i * 256;
      const int row = f >> 2, kq = (f & 3) * 8;
      *(u16x8*)&As[row][kq] = *(const u16x8*)(Ag + (size_t)row * K + kt + kq);
      *(u16x8*)&Bs[row][kq] = *(const u16x8*)(Bg + (size_t)row * K + kt + kq);
    }
    __syncthreads();

    bf16x8 a[4], b[4];
#pragma unroll
    for (int m = 0; m < 4; ++m) a[m] = *(bf16x8*)&As[wr * 64 + m * 16 + lr][lk];
#pragma unroll
    for (int n = 0; n < 4; ++n) b[n] = *(bf16x8*)&Bs[wc * 64 + n * 16 + lr][lk];
#pragma unroll
    for (int m = 0; m < 4; ++m)
#pragma unroll
      for (int n = 0; n < 4; ++n)
        acc[m][n] = __builtin_amdgcn_mfma_f32_16x16x32_bf16(a[m], b[n], acc[m][n], 0, 0, 0);
    __syncthreads();
  }

  // C/D layout: col=lane&15, row=(lane>>4)*4+reg   [HW-verified round 3]
#pragma unroll
  for (int n = 0; n < 4; ++n) {
    const int col = blockIdx.x * 128 + wc * 64 + n * 16 + lr;
    const float bv = BIAS ? bias[col] : 0.f;
#pragma unroll
    for (int m = 0; m < 4; ++m) {
      const int rbase = blockIdx.y * 128 + wr * 64 + m * 16 + (lane >> 4) * 4;
#pragma unroll
      for (int r = 0; r < 4; ++r) {
        if (OUTBF) Cb[(size_t)(rbase + r) * Nn + col] = f2bf(acc[m][n][r]);
        else       Cf[(size_t)(rbase + r) * Nn + col] = acc[m][n][r] + bv;
      }
    }
  }
}

// ---------------------------------------------------------------------------
// MFMA flash attention.  Block = 256 = 4 waves; wave w owns q-rows [w*16,w*16+16).
// Grid (N/64, B*H).  qkv [B,N,3,H,D] bf16; vt [(bh)*64+d][N] bf16.
// S = mfma(Q-frag, K-frag): lane holds S[4 q-rows (lane>>4)*4+r][key lane&15+16n].
// Row softmax: in-reg max over n-frags + shfl_xor{1,2,4,8} over 16-lane group.
// P -> LDS (per-wave slice, same-wave dep only) -> A-frags for PV.
// V^T staged from vt (coalesced), stride 72 => conflict-free b128 frag reads.
// ---------------------------------------------------------------------------
__global__ __launch_bounds__(256, 3)
void attn_mfma(const u16* __restrict__ qkv, const u16* __restrict__ vt,
               u16* __restrict__ att)
{
  __shared__ u16 Ks[64][72];
  __shared__ u16 Vs[64][72];   // V^T tile: [d][key]
  __shared__ u16 Ps[64][72];   // Q staging, then P [qrow][key]

  const int tid = threadIdx.x;
  const int lane = tid & 63, wv = tid >> 6;
  const int l15 = lane & 15, lg = lane >> 4;   // lg: k-subrange / row-group
  const int qt = blockIdx.x;
  const int bh = blockIdx.y;
  const int b = bh >> 4, h = bh & 15;

  const size_t qbase = (size_t)(b * N_ + qt * 64) * 3072 + h * 64;          // Q cols
  const size_t kcol  = (size_t)b * N_ * 3072 + 1024 + h * 64;               // K cols
  const size_t vbase = (size_t)(bh * 64) * N_;                              // vt rows

  // ---- stage Q tile into Ps, pull own wave's A-frags to registers ----
#pragma unroll
  for (int i = 0; i < 2; ++i) {
    const int f = tid + i * 256;
    const int row = f >> 3, d8 = (f & 7) * 8;
    *(u16x8*)&Ps[row][d8] = *(const u16x8*)(qkv + qbase + (size_t)row * 3072 + d8);
  }
  __syncthreads();
  bf16x8 qf[2];
#pragma unroll
  for (int ks = 0; ks < 2; ++ks) qf[ks] = *(bf16x8*)&Ps[wv * 16 + l15][ks * 32 + lg * 8];
  __syncthreads();

  f32x4 accO[4];
#pragma unroll
  for (int n = 0; n < 4; ++n) accO[n] = (f32x4){0.f, 0.f, 0.f, 0.f};
  float m[4] = {-INFINITY, -INFINITY, -INFINITY, -INFINITY};
  float l[4] = {0.f, 0.f, 0.f, 0.f};

  for (int t = 0; t < N_ / 64; ++t) {
    // ---- stage K tile [key][d] and V^T tile [d][key] (both coalesced) ----
#pragma unroll
    for (int i = 0; i < 2; ++i) {
      const int f = tid + i * 256;
      const int row = f >> 3, c8 = (f & 7) * 8;
      *(u16x8*)&Ks[row][c8] =
          *(const u16x8*)(qkv + kcol + (size_t)(t * 64 + row) * 3072 + c8);
      *(u16x8*)&Vs[row][c8] =
          *(const u16x8*)(vt + vbase + (size_t)row * N_ + t * 64 + c8);
    }
    __syncthreads();

    // ---- S = Q K^T : 4 key-frags x 2 k-steps ----
    f32x4 s[4];
#pragma unroll
    for (int n = 0; n < 4; ++n) {
      s[n] = (f32x4){0.f, 0.f, 0.f, 0.f};
#pragma unroll
      for (int ks = 0; ks < 2; ++ks) {
        const bf16x8 kf = *(bf16x8*)&Ks[n * 16 + l15][ks * 32 + lg * 8];
        s[n] = __builtin_amdgcn_mfma_f32_16x16x32_bf16(qf[ks], kf, s[n], 0, 0, 0);
      }
    }

    // ---- online softmax (rows = (lg*4+r); reduce over 16-lane group) ----
    float mx[4], scf[4], ps[4];
#pragma unroll
    for (int n = 0; n < 4; ++n)
#pragma unroll
      for (int r = 0; r < 4; ++r) s[n][r] *= 0.125f;   // 1/sqrt(64), exact
#pragma unroll
    for (int r = 0; r < 4; ++r)
      mx[r] = fmaxf(fmaxf(s[0][r], s[1][r]), fmaxf(s[2][r], s[3][r]));
#pragma unroll
    for (int mask = 1; mask < 16; mask <<= 1)
#pragma unroll
      for (int r = 0; r < 4; ++r) mx[r] = fmaxf(mx[r], __shfl_xor(mx[r], mask));
#pragma unroll
    for (int r = 0; r < 4; ++r) {
      const float mn = fmaxf(m[r], mx[r]);
      scf[r] = __expf(m[r] - mn);
      m[r] = mn;
      ps[r] = 0.f;
    }
#pragma unroll
    for (int n = 0; n < 4; ++n)
#pragma unroll
      for (int r = 0; r < 4; ++r) {
        const float p = __expf(s[n][r] - m[r]);
        s[n][r] = p;
        ps[r] += p;
      }
#pragma unroll
    for (int mask = 1; mask < 16; mask <<= 1)
#pragma unroll
      for (int r = 0; r < 4; ++r) ps[r] += __shfl_xor(ps[r], mask);
#pragma unroll
    for (int r = 0; r < 4; ++r) l[r] = l[r] * scf[r] + ps[r];
#pragma unroll
    for (int n = 0; n < 4; ++n)
#pragma unroll
      for (int r = 0; r < 4; ++r) accO[n][r] *= scf[r];

    // ---- P -> LDS (own wave's 16-row slice; same-wave dep, no barrier) ----
#pragma unroll
    for (int n = 0; n < 4; ++n)
#pragma unroll
      for (int r = 0; r < 4; ++r)
        Ps[wv * 16 + lg * 4 + r][n * 16 + l15] = f2bf(s[n][r]);

    // ---- O += P V : A = P rows (contig k), B = V^T rows (contig k) ----
#pragma unroll
    for (int ks = 0; ks < 2; ++ks) {
      const bf16x8 pa = *(bf16x8*)&Ps[wv * 16 + l15][ks * 32 + lg * 8];
#pragma unroll
      for (int n = 0; n < 4; ++n) {
        const bf16x8 vf = *(bf16x8*)&Vs[n * 16 + l15][ks * 32 + lg * 8];
        accO[n] = __builtin_amdgcn_mfma_f32_16x16x32_bf16(pa, vf, accO[n], 0, 0, 0);
      }
    }
    __syncthreads();   // protect Ks/Vs for next stage
  }

  // ---- epilogue: O /= l, store bf16 ----
  float inv[4];
#pragma unroll
  for (int r = 0; r < 4; ++r) inv[r] = 1.f / l[r];
#pragma unroll
  for (int n = 0; n < 4; ++n) {
    const int col = h * 64 + n * 16 + l15;
#pragma unroll
    for (int r = 0; r < 4; ++r) {
      const int row = b * N_ + qt * 64 + wv * 16 + lg * 4 + r;
      att[(size_t)row * C_ + col] = f2bf(accO[n][r] * inv[r]);
    }
  }
}

// ---------------------------------------------------------------------------
extern "C" void kernel_launch(void* const* d_in, const int* in_sizes, int n_in,
                              void* d_out, int out_size, void* d_ws, size_t ws_size,
                              hipStream_t stream) {
  const float* x      = (const float*)d_in[0];   // [B, N, C]
  const float* w_qkv  = (const float*)d_in[1];   // [C, 3C]
  const float* w_proj = (const float*)d_in[2];   // [C, C]
  const float* b_proj = (const float*)d_in[3];   // [C]
  float* out = (float*)d_out;                    // [B, N, C] fp32

  // ws layout (48 MB, all bf16).  vt ALIASES xb (xb dead after gemm1).
  u16* qkvb = (u16*)d_ws;                        // [4096][3072]
  u16* xb   = qkvb + (size_t)4096 * 3072;        // [4096][1024]  (later: vt)
  u16* wqt  = xb   + (size_t)4096 * 1024;        // [3072][1024] = w_qkv^T
  u16* wpt  = wqt  + (size_t)3072 * 1024;        // [1024][1024] = w_proj^T
  u16* aob  = wpt  + (size_t)1024 * 1024;        // [4096][1024]
  u16* vt   = xb;                                // [32*64][2048] = V^T per (b,h)

  const int M = B_ * N_;  // 4096

  cvt_f32_bf16<<<4096, 256, 0, stream>>>(x, xb);
  tcvt_bf16<<<dim3(96, 32), 256, 0, stream>>>(w_qkv, wqt, C_, 3 * C_);
  tcvt_bf16<<<dim3(32, 32), 256, 0, stream>>>(w_proj, wpt, C_, C_);

  // 1) QKV projection -> bf16 qkv [B,N,3,H,D]
  gemm_bf16<false, true><<<dim3(3 * C_ / 128, M / 128), 256, 0, stream>>>(
      xb, wqt, nullptr, nullptr, qkvb, M, 3 * C_, C_);

  // 1b) V^T extraction (overwrites xb region — xb is dead now)
  vtrans<<<dim3(32, 32), 256, 0, stream>>>(qkvb, vt);

  // 2) MFMA flash attention
  attn_mfma<<<dim3(N_ / 64, B_ * H_), 256, 0, stream>>>(qkvb, vt, aob);

  // 3) output projection + bias -> fp32 d_out
  gemm_bf16<true, false><<<dim3(C_ / 128, M / 128), 256, 0, stream>>>(
      aob, wpt, b_proj, out, nullptr, M, C_, C_);
}

// Round 10
// 270.977 us; speedup vs baseline: 4.1932x; 1.0228x over previous
//
#include <hip/hip_runtime.h>
#include <cstdint>
#include <cstddef>

#define B_ 2
#define N_ 2048
#define C_ 1024
#define H_ 16

typedef unsigned short u16;
typedef __attribute__((ext_vector_type(8))) short bf16x8;   // MFMA A/B frag: 8 bf16 (4 VGPR)
typedef __attribute__((ext_vector_type(4))) float f32x4;    // MFMA C/D frag
typedef __attribute__((ext_vector_type(8))) u16 u16x8;
typedef __attribute__((ext_vector_type(4))) u16 u16x4;

static __device__ __forceinline__ u16 f2bf(float f) {
  unsigned int u = __builtin_bit_cast(unsigned int, f);
  u += 0x7FFFu + ((u >> 16) & 1u);   // RNE
  return (u16)(u >> 16);
}

// ---------------------------------------------------------------------------
// elementwise fp32 -> bf16 (exact-size grid, 4 elems/thread)
// ---------------------------------------------------------------------------
__global__ void cvt_f32_bf16(const float* __restrict__ in, u16* __restrict__ out) {
  const size_t i = (size_t)(blockIdx.x * blockDim.x + threadIdx.x) * 4;
  const float4 v = *(const float4*)(in + i);
  u16x4 o;
  o[0] = f2bf(v.x); o[1] = f2bf(v.y); o[2] = f2bf(v.z); o[3] = f2bf(v.w);
  *(u16x4*)(out + i) = o;
}

// ---------------------------------------------------------------------------
// transpose + convert: in fp32 [R][Cn] -> out bf16 [Cn][R].  32x32 LDS tile.
// ---------------------------------------------------------------------------
__global__ void tcvt_bf16(const float* __restrict__ in, u16* __restrict__ out,
                          int R, int Cn) {
  __shared__ float T[32][33];
  const int t = threadIdx.x;
  const int c0 = blockIdx.x * 32, r0 = blockIdx.y * 32;
  {
    const int r = t >> 3, c4 = (t & 7) * 4;
    const float4 v = *(const float4*)(in + (size_t)(r0 + r) * Cn + c0 + c4);
    T[r][c4 + 0] = v.x; T[r][c4 + 1] = v.y; T[r][c4 + 2] = v.z; T[r][c4 + 3] = v.w;
  }
  __syncthreads();
  {
    const int c = t >> 3, r4 = (t & 7) * 4;
    u16x4 o;
    o[0] = f2bf(T[r4 + 0][c]); o[1] = f2bf(T[r4 + 1][c]);
    o[2] = f2bf(T[r4 + 2][c]); o[3] = f2bf(T[r4 + 3][c]);
    *(u16x4*)(out + (size_t)(c0 + c) * R + r0 + r4) = o;
  }
}

// ---------------------------------------------------------------------------
// V transpose: qkv [B,N,3,H,D] bf16 V-part -> vt [(b*16+h)*64+d][N] bf16.
// ---------------------------------------------------------------------------
__global__ __launch_bounds__(256, 4)
void vtrans(const u16* __restrict__ qkv, u16* __restrict__ vt) {
  __shared__ u16 T[64][72];
  const int tid = threadIdx.x;
  const int bh = blockIdx.x, tile = blockIdx.y;
  const int b = bh >> 4, h = bh & 15;
  const size_t src = (size_t)(b * N_ + tile * 64) * 3072 + 2048 + h * 64;
#pragma unroll
  for (int i = 0; i < 2; ++i) {
    const int f = tid + i * 256;
    const int row = f >> 3, d8 = (f & 7) * 8;
    *(u16x8*)&T[row][d8] = *(const u16x8*)(qkv + src + (size_t)row * 3072 + d8);
  }
  __syncthreads();
#pragma unroll
  for (int i = 0; i < 2; ++i) {
    const int f = tid + i * 256;
    const int d = f >> 3, n8 = (f & 7) * 8;
    u16x8 o;
#pragma unroll
    for (int j = 0; j < 8; ++j) o[j] = T[n8 + j][d];
    *(u16x8*)(vt + (size_t)(bh * 64 + d) * N_ + tile * 64 + n8) = o;
  }
}

// ---------------------------------------------------------------------------
// bf16 MFMA GEMM: C[M,Nn] = A[M,K] @ B[K,Nn], A row-major bf16, Bt = B^T
// row-major bf16 ([Nn][K]).  128x128 tile, BK=32, 4 waves (2x2), 4x4 frags.
// ---------------------------------------------------------------------------
template<bool BIAS, bool OUTBF>
__global__ __launch_bounds__(256, 2)
void gemm_bf16(const u16* __restrict__ A, const u16* __restrict__ Bt,
               const float* __restrict__ bias, float* __restrict__ Cf,
               u16* __restrict__ Cb, int M, int Nn, int K)
{
  __shared__ u16 As[128][40];
  __shared__ u16 Bs[128][40];

  const int tid = threadIdx.x;
  const int lane = tid & 63, wv = tid >> 6;
  const int wr = wv >> 1, wc = wv & 1;
  const int lr = lane & 15, lk = (lane >> 4) * 8;

  f32x4 acc[4][4];
#pragma unroll
  for (int m = 0; m < 4; ++m)
#pragma unroll
    for (int n = 0; n < 4; ++n) acc[m][n] = (f32x4){0.f, 0.f, 0.f, 0.f};

  const u16* Ag = A + (size_t)(blockIdx.y * 128) * K;
  const u16* Bg = Bt + (size_t)(blockIdx.x * 128) * K;

  for (int kt = 0; kt < K; kt += 32) {
#pragma unroll
    for (int i = 0; i < 2; ++i) {
      const int f = tid + i * 256;
      const int row = f >> 2, kq = (f & 3) * 8;
      *(u16x8*)&As[row][kq] = *(const u16x8*)(Ag + (size_t)row * K + kt + kq);
      *(u16x8*)&Bs[row][kq] = *(const u16x8*)(Bg + (size_t)row * K + kt + kq);
    }
    __syncthreads();

    bf16x8 a[4], b[4];
#pragma unroll
    for (int m = 0; m < 4; ++m) a[m] = *(bf16x8*)&As[wr * 64 + m * 16 + lr][lk];
#pragma unroll
    for (int n = 0; n < 4; ++n) b[n] = *(bf16x8*)&Bs[wc * 64 + n * 16 + lr][lk];
#pragma unroll
    for (int m = 0; m < 4; ++m)
#pragma unroll
      for (int n = 0; n < 4; ++n)
        acc[m][n] = __builtin_amdgcn_mfma_f32_16x16x32_bf16(a[m], b[n], acc[m][n], 0, 0, 0);
    __syncthreads();
  }

  // C/D layout: col=lane&15, row=(lane>>4)*4+reg   [HW-verified round 3]
#pragma unroll
  for (int n = 0; n < 4; ++n) {
    const int col = blockIdx.x * 128 + wc * 64 + n * 16 + lr;
    const float bv = BIAS ? bias[col] : 0.f;
#pragma unroll
    for (int m = 0; m < 4; ++m) {
      const int rbase = blockIdx.y * 128 + wr * 64 + m * 16 + (lane >> 4) * 4;
#pragma unroll
      for (int r = 0; r < 4; ++r) {
        if (OUTBF) Cb[(size_t)(rbase + r) * Nn + col] = f2bf(acc[m][n][r]);
        else       Cf[(size_t)(rbase + r) * Nn + col] = acc[m][n][r] + bv;
      }
    }
  }
}

// ---------------------------------------------------------------------------
// MFMA flash attention, double-buffered K/V, 1 barrier/iter, XCD-swizzled.
// Block = 256 = 4 waves; wave w owns q-rows [w*16, w*16+16).  Grid (1024).
// swz = (bid&7)*128 + bid>>3  => each XCD gets 4 consecutive bh's (L2-fit).
// S = mfma(Q-frag, K-frag): lane holds S[4 q-rows (lg*4+r)][key l15+16n].
// Row softmax via shfl_xor{1,2,4,8} over 16-lane group.
// P -> per-wave LDS slice (same-wave dep) -> A-frags for PV.
// ---------------------------------------------------------------------------
__global__ __launch_bounds__(256, 3)
void attn_mfma(const u16* __restrict__ qkv, const u16* __restrict__ vt,
               u16* __restrict__ att)
{
  __shared__ u16 Ks[2][64][72];
  __shared__ u16 Vs[2][64][72];   // V^T tile: [d][key]
  __shared__ u16 Ps[64][72];      // Q staging, then P [qrow][key]

  const int tid = threadIdx.x;
  const int lane = tid & 63, wv = tid >> 6;
  const int l15 = lane & 15, lg = lane >> 4;
  const int bid = blockIdx.x;
  const int swz = (bid & 7) * 128 + (bid >> 3);   // 1024 % 8 == 0: bijective
  const int bh = swz >> 5, qt = swz & 31;
  const int b = bh >> 4, h = bh & 15;

  const size_t qbase = (size_t)(b * N_ + qt * 64) * 3072 + h * 64;
  const size_t kcol  = (size_t)b * N_ * 3072 + 1024 + h * 64;
  const size_t vbase = (size_t)(bh * 64) * N_;

  // staging indices (shared by Q/K/V paths)
  const int f0 = tid, f1 = tid + 256;
  const int row0 = f0 >> 3, c80 = (f0 & 7) * 8;
  const int row1 = f1 >> 3, c81 = (f1 & 7) * 8;

  // ---- prologue: stage Q into Ps and K/V tile 0 into buf 0 ----
  *(u16x8*)&Ps[row0][c80] = *(const u16x8*)(qkv + qbase + (size_t)row0 * 3072 + c80);
  *(u16x8*)&Ps[row1][c81] = *(const u16x8*)(qkv + qbase + (size_t)row1 * 3072 + c81);
  *(u16x8*)&Ks[0][row0][c80] = *(const u16x8*)(qkv + kcol + (size_t)row0 * 3072 + c80);
  *(u16x8*)&Ks[0][row1][c81] = *(const u16x8*)(qkv + kcol + (size_t)row1 * 3072 + c81);
  *(u16x8*)&Vs[0][row0][c80] = *(const u16x8*)(vt + vbase + (size_t)row0 * N_ + c80);
  *(u16x8*)&Vs[0][row1][c81] = *(const u16x8*)(vt + vbase + (size_t)row1 * N_ + c81);
  __syncthreads();
  bf16x8 qf[2];
#pragma unroll
  for (int ks = 0; ks < 2; ++ks) qf[ks] = *(bf16x8*)&Ps[wv * 16 + l15][ks * 32 + lg * 8];
  __syncthreads();   // qf reads complete before iter-0 P-stores into Ps

  f32x4 accO[4];
#pragma unroll
  for (int n = 0; n < 4; ++n) accO[n] = (f32x4){0.f, 0.f, 0.f, 0.f};
  float m[4] = {-INFINITY, -INFINITY, -INFINITY, -INFINITY};
  float l[4] = {0.f, 0.f, 0.f, 0.f};

  for (int t = 0; t < N_ / 64; ++t) {
    const int cur = t & 1;

    // ---- issue next tile's global loads into registers (latency hidden) ----
    u16x8 k0, k1, v0, v1;
    if (t + 1 < N_ / 64) {
      const size_t krow = kcol + (size_t)((t + 1) * 64) * 3072;
      k0 = *(const u16x8*)(qkv + krow + (size_t)row0 * 3072 + c80);
      k1 = *(const u16x8*)(qkv + krow + (size_t)row1 * 3072 + c81);
      v0 = *(const u16x8*)(vt + vbase + (size_t)row0 * N_ + (t + 1) * 64 + c80);
      v1 = *(const u16x8*)(vt + vbase + (size_t)row1 * N_ + (t + 1) * 64 + c81);
    }

    // ---- S = Q K^T : 4 key-frags x 2 k-steps ----
    f32x4 s[4];
#pragma unroll
    for (int n = 0; n < 4; ++n) {
      s[n] = (f32x4){0.f, 0.f, 0.f, 0.f};
#pragma unroll
      for (int ks = 0; ks < 2; ++ks) {
        const bf16x8 kf = *(bf16x8*)&Ks[cur][n * 16 + l15][ks * 32 + lg * 8];
        s[n] = __builtin_amdgcn_mfma_f32_16x16x32_bf16(qf[ks], kf, s[n], 0, 0, 0);
      }
    }

    // ---- online softmax (rows = lg*4+r; reduce over 16-lane group) ----
    float mx[4], scf[4], ps[4];
#pragma unroll
    for (int n = 0; n < 4; ++n)
#pragma unroll
      for (int r = 0; r < 4; ++r) s[n][r] *= 0.125f;   // 1/sqrt(64), exact
#pragma unroll
    for (int r = 0; r < 4; ++r)
      mx[r] = fmaxf(fmaxf(s[0][r], s[1][r]), fmaxf(s[2][r], s[3][r]));
#pragma unroll
    for (int mask = 1; mask < 16; mask <<= 1)
#pragma unroll
      for (int r = 0; r < 4; ++r) mx[r] = fmaxf(mx[r], __shfl_xor(mx[r], mask));
#pragma unroll
    for (int r = 0; r < 4; ++r) {
      const float mn = fmaxf(m[r], mx[r]);
      scf[r] = __expf(m[r] - mn);
      m[r] = mn;
      ps[r] = 0.f;
    }
#pragma unroll
    for (int n = 0; n < 4; ++n)
#pragma unroll
      for (int r = 0; r < 4; ++r) {
        const float p = __expf(s[n][r] - m[r]);
        s[n][r] = p;
        ps[r] += p;
      }
#pragma unroll
    for (int mask = 1; mask < 16; mask <<= 1)
#pragma unroll
      for (int r = 0; r < 4; ++r) ps[r] += __shfl_xor(ps[r], mask);
#pragma unroll
    for (int r = 0; r < 4; ++r) l[r] = l[r] * scf[r] + ps[r];
#pragma unroll
    for (int n = 0; n < 4; ++n)
#pragma unroll
      for (int r = 0; r < 4; ++r) accO[n][r] *= scf[r];

    // ---- P -> LDS (own wave's 16-row slice; same-wave dep only) ----
#pragma unroll
    for (int n = 0; n < 4; ++n)
#pragma unroll
      for (int r = 0; r < 4; ++r)
        Ps[wv * 16 + lg * 4 + r][n * 16 + l15] = f2bf(s[n][r]);

    // ---- O += P V ----
#pragma unroll
    for (int ks = 0; ks < 2; ++ks) {
      const bf16x8 pa = *(bf16x8*)&Ps[wv * 16 + l15][ks * 32 + lg * 8];
#pragma unroll
      for (int n = 0; n < 4; ++n) {
        const bf16x8 vf = *(bf16x8*)&Vs[cur][n * 16 + l15][ks * 32 + lg * 8];
        accO[n] = __builtin_amdgcn_mfma_f32_16x16x32_bf16(pa, vf, accO[n], 0, 0, 0);
      }
    }

    // ---- write prefetched tile into alternate buffer ----
    // Safe with ONE barrier/iter: last readers of buf[cur^1] ran in iter t-1,
    // separated from these writes by iter t-1's barrier.
    if (t + 1 < N_ / 64) {
      *(u16x8*)&Ks[cur ^ 1][row0][c80] = k0;
      *(u16x8*)&Ks[cur ^ 1][row1][c81] = k1;
      *(u16x8*)&Vs[cur ^ 1][row0][c80] = v0;
      *(u16x8*)&Vs[cur ^ 1][row1][c81] = v1;
    }
    __syncthreads();
  }

  // ---- epilogue: O /= l, store bf16 ----
  float inv[4];
#pragma unroll
  for (int r = 0; r < 4; ++r) inv[r] = 1.f / l[r];
#pragma unroll
  for (int n = 0; n < 4; ++n) {
    const int col = h * 64 + n * 16 + l15;
#pragma unroll
    for (int r = 0; r < 4; ++r) {
      const int row = b * N_ + qt * 64 + wv * 16 + lg * 4 + r;
      att[(size_t)row * C_ + col] = f2bf(accO[n][r] * inv[r]);
    }
  }
}

// ---------------------------------------------------------------------------
extern "C" void kernel_launch(void* const* d_in, const int* in_sizes, int n_in,
                              void* d_out, int out_size, void* d_ws, size_t ws_size,
                              hipStream_t stream) {
  const float* x      = (const float*)d_in[0];   // [B, N, C]
  const float* w_qkv  = (const float*)d_in[1];   // [C, 3C]
  const float* w_proj = (const float*)d_in[2];   // [C, C]
  const float* b_proj = (const float*)d_in[3];   // [C]
  float* out = (float*)d_out;                    // [B, N, C] fp32

  // ws layout (48 MB, all bf16).  vt ALIASES xb (xb dead after gemm1).
  u16* qkvb = (u16*)d_ws;                        // [4096][3072]
  u16* xb   = qkvb + (size_t)4096 * 3072;        // [4096][1024]  (later: vt)
  u16* wqt  = xb   + (size_t)4096 * 1024;        // [3072][1024] = w_qkv^T
  u16* wpt  = wqt  + (size_t)3072 * 1024;        // [1024][1024] = w_proj^T
  u16* aob  = wpt  + (size_t)1024 * 1024;        // [4096][1024]
  u16* vt   = xb;                                // [32*64][2048] = V^T per (b,h)

  const int M = B_ * N_;  // 4096

  cvt_f32_bf16<<<4096, 256, 0, stream>>>(x, xb);
  tcvt_bf16<<<dim3(96, 32), 256, 0, stream>>>(w_qkv, wqt, C_, 3 * C_);
  tcvt_bf16<<<dim3(32, 32), 256, 0, stream>>>(w_proj, wpt, C_, C_);

  // 1) QKV projection -> bf16 qkv [B,N,3,H,D]
  gemm_bf16<false, true><<<dim3(3 * C_ / 128, M / 128), 256, 0, stream>>>(
      xb, wqt, nullptr, nullptr, qkvb, M, 3 * C_, C_);

  // 1b) V^T extraction (overwrites xb region — xb is dead now)
  vtrans<<<dim3(32, 32), 256, 0, stream>>>(qkvb, vt);

  // 2) MFMA flash attention (dbuf + XCD swizzle)
  attn_mfma<<<dim3(N_ / 64 * B_ * H_), 256, 0, stream>>>(qkvb, vt, aob);

  // 3) output projection + bias -> fp32 d_out
  gemm_bf16<true, false><<<dim3(C_ / 128, M / 128), 256, 0, stream>>>(
      aob, wpt, b_proj, out, nullptr, M, C_, C_);
}

// Round 11
// 266.527 us; speedup vs baseline: 4.2632x; 1.0167x over previous
//
#include <hip/hip_runtime.h>
#include <cstdint>
#include <cstddef>

#define B_ 2
#define N_ 2048
#define C_ 1024
#define H_ 16
#define QSCALE 0.18033688f   // 0.125 * log2(e): softmax runs in exp2 domain

typedef unsigned short u16;
typedef __attribute__((ext_vector_type(8))) short bf16x8;   // MFMA A/B frag
typedef __attribute__((ext_vector_type(4))) float f32x4;    // MFMA C/D frag
typedef __attribute__((ext_vector_type(8))) u16 u16x8;
typedef __attribute__((ext_vector_type(4))) u16 u16x4;

static __device__ __forceinline__ u16 f2bf(float f) {
  unsigned int u = __builtin_bit_cast(unsigned int, f);
  u += 0x7FFFu + ((u >> 16) & 1u);   // RNE
  return (u16)(u >> 16);
}

// ---------------------------------------------------------------------------
// elementwise fp32 -> bf16 (exact-size grid, 4 elems/thread)
// ---------------------------------------------------------------------------
__global__ void cvt_f32_bf16(const float* __restrict__ in, u16* __restrict__ out) {
  const size_t i = (size_t)(blockIdx.x * blockDim.x + threadIdx.x) * 4;
  const float4 v = *(const float4*)(in + i);
  u16x4 o;
  o[0] = f2bf(v.x); o[1] = f2bf(v.y); o[2] = f2bf(v.z); o[3] = f2bf(v.w);
  *(u16x4*)(out + i) = o;
}

// ---------------------------------------------------------------------------
// transpose + convert: in fp32 [R][Cn] -> out bf16 [Cn][R].  32x32 LDS tile.
// ---------------------------------------------------------------------------
__global__ void tcvt_bf16(const float* __restrict__ in, u16* __restrict__ out,
                          int R, int Cn) {
  __shared__ float T[32][33];
  const int t = threadIdx.x;
  const int c0 = blockIdx.x * 32, r0 = blockIdx.y * 32;
  {
    const int r = t >> 3, c4 = (t & 7) * 4;
    const float4 v = *(const float4*)(in + (size_t)(r0 + r) * Cn + c0 + c4);
    T[r][c4 + 0] = v.x; T[r][c4 + 1] = v.y; T[r][c4 + 2] = v.z; T[r][c4 + 3] = v.w;
  }
  __syncthreads();
  {
    const int c = t >> 3, r4 = (t & 7) * 4;
    u16x4 o;
    o[0] = f2bf(T[r4 + 0][c]); o[1] = f2bf(T[r4 + 1][c]);
    o[2] = f2bf(T[r4 + 2][c]); o[3] = f2bf(T[r4 + 3][c]);
    *(u16x4*)(out + (size_t)(c0 + c) * R + r0 + r4) = o;
  }
}

// ---------------------------------------------------------------------------
// V transpose: qkv [B,N,3,H,D] bf16 V-part -> vt [(b*16+h)*64+d][N] bf16.
// ---------------------------------------------------------------------------
__global__ __launch_bounds__(256, 4)
void vtrans(const u16* __restrict__ qkv, u16* __restrict__ vt) {
  __shared__ u16 T[64][72];
  const int tid = threadIdx.x;
  const int bh = blockIdx.x, tile = blockIdx.y;
  const int b = bh >> 4, h = bh & 15;
  const size_t src = (size_t)(b * N_ + tile * 64) * 3072 + 2048 + h * 64;
#pragma unroll
  for (int i = 0; i < 2; ++i) {
    const int f = tid + i * 256;
    const int row = f >> 3, d8 = (f & 7) * 8;
    *(u16x8*)&T[row][d8] = *(const u16x8*)(qkv + src + (size_t)row * 3072 + d8);
  }
  __syncthreads();
#pragma unroll
  for (int i = 0; i < 2; ++i) {
    const int f = tid + i * 256;
    const int d = f >> 3, n8 = (f & 7) * 8;
    u16x8 o;
#pragma unroll
    for (int j = 0; j < 8; ++j) o[j] = T[n8 + j][d];
    *(u16x8*)(vt + (size_t)(bh * 64 + d) * N_ + tile * 64 + n8) = o;
  }
}

// ---------------------------------------------------------------------------
// bf16 MFMA GEMM: C[M,Nn] = A[M,K] @ B[K,Nn].  When OUTBF, columns < 1024 are
// scaled by qscale (folds softmax 1/sqrt(d)*log2e into the Q part of QKV).
// ---------------------------------------------------------------------------
template<bool BIAS, bool OUTBF>
__global__ __launch_bounds__(256, 2)
void gemm_bf16(const u16* __restrict__ A, const u16* __restrict__ Bt,
               const float* __restrict__ bias, float* __restrict__ Cf,
               u16* __restrict__ Cb, int M, int Nn, int K, float qscale)
{
  __shared__ u16 As[128][40];
  __shared__ u16 Bs[128][40];

  const int tid = threadIdx.x;
  const int lane = tid & 63, wv = tid >> 6;
  const int wr = wv >> 1, wc = wv & 1;
  const int lr = lane & 15, lk = (lane >> 4) * 8;

  f32x4 acc[4][4];
#pragma unroll
  for (int m = 0; m < 4; ++m)
#pragma unroll
    for (int n = 0; n < 4; ++n) acc[m][n] = (f32x4){0.f, 0.f, 0.f, 0.f};

  const u16* Ag = A + (size_t)(blockIdx.y * 128) * K;
  const u16* Bg = Bt + (size_t)(blockIdx.x * 128) * K;

  for (int kt = 0; kt < K; kt += 32) {
#pragma unroll
    for (int i = 0; i < 2; ++i) {
      const int f = tid + i * 256;
      const int row = f >> 2, kq = (f & 3) * 8;
      *(u16x8*)&As[row][kq] = *(const u16x8*)(Ag + (size_t)row * K + kt + kq);
      *(u16x8*)&Bs[row][kq] = *(const u16x8*)(Bg + (size_t)row * K + kt + kq);
    }
    __syncthreads();

    bf16x8 a[4], b[4];
#pragma unroll
    for (int m = 0; m < 4; ++m) a[m] = *(bf16x8*)&As[wr * 64 + m * 16 + lr][lk];
#pragma unroll
    for (int n = 0; n < 4; ++n) b[n] = *(bf16x8*)&Bs[wc * 64 + n * 16 + lr][lk];
#pragma unroll
    for (int m = 0; m < 4; ++m)
#pragma unroll
      for (int n = 0; n < 4; ++n)
        acc[m][n] = __builtin_amdgcn_mfma_f32_16x16x32_bf16(a[m], b[n], acc[m][n], 0, 0, 0);
    __syncthreads();
  }

  // C/D layout: col=lane&15, row=(lane>>4)*4+reg   [HW-verified round 3]
#pragma unroll
  for (int n = 0; n < 4; ++n) {
    const int col = blockIdx.x * 128 + wc * 64 + n * 16 + lr;
    const float bv = BIAS ? bias[col] : 0.f;
    const float sc = (OUTBF && col < 1024) ? qscale : 1.0f;
#pragma unroll
    for (int m = 0; m < 4; ++m) {
      const int rbase = blockIdx.y * 128 + wr * 64 + m * 16 + (lane >> 4) * 4;
#pragma unroll
      for (int r = 0; r < 4; ++r) {
        if (OUTBF) Cb[(size_t)(rbase + r) * Nn + col] = f2bf(acc[m][n][r] * sc);
        else       Cf[(size_t)(rbase + r) * Nn + col] = acc[m][n][r] + bv;
      }
    }
  }
}

// ---------------------------------------------------------------------------
// MFMA flash attention.  8 waves, QBLK=128 q-rows/block (wave w: rows w*16..+16),
// KVBLK=64, K/V reg-prefetch double-buffer, 1 barrier/iter, XCD swizzle.
// Q pre-scaled by 0.125*log2e in gemm1 => softmax in exp2 domain.
// Defer-max (THR=11 in exp2 domain) skips rescale when max growth is small.
// Grid (512).  swz=(bid&7)*64+bid>>3: each XCD gets 4 consecutive bh (L2-fit).
// ---------------------------------------------------------------------------
__global__ __launch_bounds__(512, 2)
void attn_mfma(const u16* __restrict__ qkv, const u16* __restrict__ vt,
               u16* __restrict__ att)
{
  __shared__ u16 Ks[2][64][72];
  __shared__ u16 Vs[2][64][72];   // V^T tile: [d][key]
  __shared__ u16 Ps[128][72];     // Q staging, then P [qrow][key]

  const int tid = threadIdx.x;
  const int lane = tid & 63, wv = tid >> 6;     // 8 waves
  const int l15 = lane & 15, lg = lane >> 4;
  const int bid = blockIdx.x;
  const int swz = (bid & 7) * 64 + (bid >> 3);  // 512 % 8 == 0: bijective
  const int bh = swz >> 4, qt = swz & 15;
  const int b = bh >> 4, h = bh & 15;

  const size_t qbase = (size_t)(b * N_ + qt * 128) * 3072 + h * 64;
  const size_t kcol  = (size_t)b * N_ * 3072 + 1024 + h * 64;
  const size_t vbase = (size_t)(bh * 64) * N_;

  // staging: 512 threads cover a 64x64 bf16 tile with one u16x8 each
  const int srow = tid >> 3, sc8 = (tid & 7) * 8;

  // ---- prologue: stage Q (128x64) into Ps and K/V tile 0 into buf 0 ----
  *(u16x8*)&Ps[srow][sc8]      = *(const u16x8*)(qkv + qbase + (size_t)srow * 3072 + sc8);
  *(u16x8*)&Ps[64 + srow][sc8] = *(const u16x8*)(qkv + qbase + (size_t)(64 + srow) * 3072 + sc8);
  *(u16x8*)&Ks[0][srow][sc8]   = *(const u16x8*)(qkv + kcol + (size_t)srow * 3072 + sc8);
  *(u16x8*)&Vs[0][srow][sc8]   = *(const u16x8*)(vt + vbase + (size_t)srow * N_ + sc8);
  __syncthreads();
  bf16x8 qf[2];
#pragma unroll
  for (int ks = 0; ks < 2; ++ks) qf[ks] = *(bf16x8*)&Ps[wv * 16 + l15][ks * 32 + lg * 8];
  __syncthreads();   // qf reads complete before iter-0 P-stores into Ps

  f32x4 accO[4];
#pragma unroll
  for (int n = 0; n < 4; ++n) accO[n] = (f32x4){0.f, 0.f, 0.f, 0.f};
  float m[4] = {-INFINITY, -INFINITY, -INFINITY, -INFINITY};
  float l[4] = {0.f, 0.f, 0.f, 0.f};

  for (int t = 0; t < N_ / 64; ++t) {
    const int cur = t & 1;

    // ---- issue next tile's global loads (latency hidden under compute) ----
    u16x8 kpre, vpre;
    if (t + 1 < N_ / 64) {
      kpre = *(const u16x8*)(qkv + kcol + (size_t)((t + 1) * 64 + srow) * 3072 + sc8);
      vpre = *(const u16x8*)(vt + vbase + (size_t)srow * N_ + (t + 1) * 64 + sc8);
    }

    // ---- S = Q K^T (exp2-domain scores; scale pre-folded into Q) ----
    f32x4 s[4];
    __builtin_amdgcn_s_setprio(1);
#pragma unroll
    for (int n = 0; n < 4; ++n) {
      s[n] = (f32x4){0.f, 0.f, 0.f, 0.f};
#pragma unroll
      for (int ks = 0; ks < 2; ++ks) {
        const bf16x8 kf = *(bf16x8*)&Ks[cur][n * 16 + l15][ks * 32 + lg * 8];
        s[n] = __builtin_amdgcn_mfma_f32_16x16x32_bf16(qf[ks], kf, s[n], 0, 0, 0);
      }
    }
    __builtin_amdgcn_s_setprio(0);

    // ---- online softmax, exp2 domain, defer-max ----
    float mx[4];
#pragma unroll
    for (int r = 0; r < 4; ++r)
      mx[r] = fmaxf(fmaxf(s[0][r], s[1][r]), fmaxf(s[2][r], s[3][r]));
#pragma unroll
    for (int mask = 1; mask < 16; mask <<= 1)
#pragma unroll
      for (int r = 0; r < 4; ++r) mx[r] = fmaxf(mx[r], __shfl_xor(mx[r], mask));

    bool ok = true;
#pragma unroll
    for (int r = 0; r < 4; ++r) ok = ok && (mx[r] <= m[r] + 11.0f);
    const bool skip = __all(ok);   // wave-uniform

    float scf[4];
    if (!skip) {
#pragma unroll
      for (int r = 0; r < 4; ++r) {
        const float mn = fmaxf(m[r], mx[r]);
        scf[r] = exp2f(m[r] - mn);
        m[r] = mn;
      }
    }
    float ps[4] = {0.f, 0.f, 0.f, 0.f};
#pragma unroll
    for (int n = 0; n < 4; ++n)
#pragma unroll
      for (int r = 0; r < 4; ++r) {
        const float p = exp2f(s[n][r] - m[r]);   // bounded by 2^11 when deferred
        s[n][r] = p;
        ps[r] += p;
      }
#pragma unroll
    for (int mask = 1; mask < 16; mask <<= 1)
#pragma unroll
      for (int r = 0; r < 4; ++r) ps[r] += __shfl_xor(ps[r], mask);
    if (skip) {
#pragma unroll
      for (int r = 0; r < 4; ++r) l[r] += ps[r];
    } else {
#pragma unroll
      for (int r = 0; r < 4; ++r) l[r] = l[r] * scf[r] + ps[r];
#pragma unroll
      for (int n = 0; n < 4; ++n)
#pragma unroll
        for (int r = 0; r < 4; ++r) accO[n][r] *= scf[r];
    }

    // ---- P -> LDS (own wave's 16-row slice; same-wave dep only) ----
#pragma unroll
    for (int n = 0; n < 4; ++n)
#pragma unroll
      for (int r = 0; r < 4; ++r)
        Ps[wv * 16 + lg * 4 + r][n * 16 + l15] = f2bf(s[n][r]);

    // ---- O += P V ----
    __builtin_amdgcn_s_setprio(1);
#pragma unroll
    for (int ks = 0; ks < 2; ++ks) {
      const bf16x8 pa = *(bf16x8*)&Ps[wv * 16 + l15][ks * 32 + lg * 8];
#pragma unroll
      for (int n = 0; n < 4; ++n) {
        const bf16x8 vf = *(bf16x8*)&Vs[cur][n * 16 + l15][ks * 32 + lg * 8];
        accO[n] = __builtin_amdgcn_mfma_f32_16x16x32_bf16(pa, vf, accO[n], 0, 0, 0);
      }
    }
    __builtin_amdgcn_s_setprio(0);

    // ---- write prefetched tile into alternate buffer ----
    // Safe with ONE barrier/iter: last readers of buf[cur^1] ran in iter t-1,
    // separated from these writes by iter t-1's barrier.
    if (t + 1 < N_ / 64) {
      *(u16x8*)&Ks[cur ^ 1][srow][sc8] = kpre;
      *(u16x8*)&Vs[cur ^ 1][srow][sc8] = vpre;
    }
    __syncthreads();
  }

  // ---- epilogue: O /= l, store bf16 ----
  float inv[4];
#pragma unroll
  for (int r = 0; r < 4; ++r) inv[r] = 1.f / l[r];
#pragma unroll
  for (int n = 0; n < 4; ++n) {
    const int col = h * 64 + n * 16 + l15;
#pragma unroll
    for (int r = 0; r < 4; ++r) {
      const int row = b * N_ + qt * 128 + wv * 16 + lg * 4 + r;
      att[(size_t)row * C_ + col] = f2bf(accO[n][r] * inv[r]);
    }
  }
}

// ---------------------------------------------------------------------------
extern "C" void kernel_launch(void* const* d_in, const int* in_sizes, int n_in,
                              void* d_out, int out_size, void* d_ws, size_t ws_size,
                              hipStream_t stream) {
  const float* x      = (const float*)d_in[0];   // [B, N, C]
  const float* w_qkv  = (const float*)d_in[1];   // [C, 3C]
  const float* w_proj = (const float*)d_in[2];   // [C, C]
  const float* b_proj = (const float*)d_in[3];   // [C]
  float* out = (float*)d_out;                    // [B, N, C] fp32

  // ws layout (48 MB, all bf16).  vt ALIASES xb (xb dead after gemm1).
  u16* qkvb = (u16*)d_ws;                        // [4096][3072]  (Q part pre-scaled)
  u16* xb   = qkvb + (size_t)4096 * 3072;        // [4096][1024]  (later: vt)
  u16* wqt  = xb   + (size_t)4096 * 1024;        // [3072][1024] = w_qkv^T
  u16* wpt  = wqt  + (size_t)3072 * 1024;        // [1024][1024] = w_proj^T
  u16* aob  = wpt  + (size_t)1024 * 1024;        // [4096][1024]
  u16* vt   = xb;                                // [32*64][2048] = V^T per (b,h)

  const int M = B_ * N_;  // 4096

  cvt_f32_bf16<<<4096, 256, 0, stream>>>(x, xb);
  tcvt_bf16<<<dim3(96, 32), 256, 0, stream>>>(w_qkv, wqt, C_, 3 * C_);
  tcvt_bf16<<<dim3(32, 32), 256, 0, stream>>>(w_proj, wpt, C_, C_);

  // 1) QKV projection -> bf16 qkv [B,N,3,H,D], Q columns pre-scaled
  gemm_bf16<false, true><<<dim3(3 * C_ / 128, M / 128), 256, 0, stream>>>(
      xb, wqt, nullptr, nullptr, qkvb, M, 3 * C_, C_, QSCALE);

  // 1b) V^T extraction (overwrites xb region — xb is dead now)
  vtrans<<<dim3(32, 32), 256, 0, stream>>>(qkvb, vt);

  // 2) MFMA flash attention (8-wave QBLK=128, dbuf, swizzle, exp2 softmax)
  attn_mfma<<<dim3(N_ / 128 * B_ * H_), 512, 0, stream>>>(qkvb, vt, aob);

  // 3) output projection + bias -> fp32 d_out
  gemm_bf16<true, false><<<dim3(C_ / 128, M / 128), 256, 0, stream>>>(
      aob, wpt, b_proj, out, nullptr, M, C_, C_, 1.0f);
}

// Round 13
// 222.299 us; speedup vs baseline: 5.1114x; 1.1990x over previous
//
#include <hip/hip_runtime.h>
#include <cstdint>
#include <cstddef>

#define B_ 2
#define N_ 2048
#define C_ 1024
#define H_ 16
#define QSCALE 0.18033688f   // 0.125 * log2(e): softmax runs in exp2 domain

typedef unsigned short u16;
typedef __attribute__((ext_vector_type(8))) short bf16x8;   // MFMA A/B frag
typedef __attribute__((ext_vector_type(4))) float f32x4;    // MFMA C/D frag
typedef __attribute__((ext_vector_type(8))) u16 u16x8;
typedef __attribute__((ext_vector_type(4))) u16 u16x4;

static __device__ __forceinline__ u16 f2bf(float f) {
  unsigned int u = __builtin_bit_cast(unsigned int, f);
  u += 0x7FFFu + ((u >> 16) & 1u);   // RNE
  return (u16)(u >> 16);
}

// ---------------------------------------------------------------------------
// elementwise fp32 -> bf16 (exact-size grid, 4 elems/thread)
// ---------------------------------------------------------------------------
__global__ void cvt_f32_bf16(const float* __restrict__ in, u16* __restrict__ out) {
  const size_t i = (size_t)(blockIdx.x * blockDim.x + threadIdx.x) * 4;
  const float4 v = *(const float4*)(in + i);
  u16x4 o;
  o[0] = f2bf(v.x); o[1] = f2bf(v.y); o[2] = f2bf(v.z); o[3] = f2bf(v.w);
  *(u16x4*)(out + i) = o;
}

// ---------------------------------------------------------------------------
// transpose + convert: in fp32 [R][Cn] -> out bf16 [Cn][R].  32x32 LDS tile.
// ---------------------------------------------------------------------------
__global__ void tcvt_bf16(const float* __restrict__ in, u16* __restrict__ out,
                          int R, int Cn) {
  __shared__ float T[32][33];
  const int t = threadIdx.x;
  const int c0 = blockIdx.x * 32, r0 = blockIdx.y * 32;
  {
    const int r = t >> 3, c4 = (t & 7) * 4;
    const float4 v = *(const float4*)(in + (size_t)(r0 + r) * Cn + c0 + c4);
    T[r][c4 + 0] = v.x; T[r][c4 + 1] = v.y; T[r][c4 + 2] = v.z; T[r][c4 + 3] = v.w;
  }
  __syncthreads();
  {
    const int c = t >> 3, r4 = (t & 7) * 4;
    u16x4 o;
    o[0] = f2bf(T[r4 + 0][c]); o[1] = f2bf(T[r4 + 1][c]);
    o[2] = f2bf(T[r4 + 2][c]); o[3] = f2bf(T[r4 + 3][c]);
    *(u16x4*)(out + (size_t)(c0 + c) * R + r0 + r4) = o;
  }
}

// ---------------------------------------------------------------------------
// V transpose: qkv [B,N,3,H,D] bf16 V-part -> vt [(b*16+h)*64+d][N] bf16.
// ---------------------------------------------------------------------------
__global__ __launch_bounds__(256, 4)
void vtrans(const u16* __restrict__ qkv, u16* __restrict__ vt) {
  __shared__ u16 T[64][72];
  const int tid = threadIdx.x;
  const int bh = blockIdx.x, tile = blockIdx.y;
  const int b = bh >> 4, h = bh & 15;
  const size_t src = (size_t)(b * N_ + tile * 64) * 3072 + 2048 + h * 64;
#pragma unroll
  for (int i = 0; i < 2; ++i) {
    const int f = tid + i * 256;
    const int row = f >> 3, d8 = (f & 7) * 8;
    *(u16x8*)&T[row][d8] = *(const u16x8*)(qkv + src + (size_t)row * 3072 + d8);
  }
  __syncthreads();
#pragma unroll
  for (int i = 0; i < 2; ++i) {
    const int f = tid + i * 256;
    const int d = f >> 3, n8 = (f & 7) * 8;
    u16x8 o;
#pragma unroll
    for (int j = 0; j < 8; ++j) o[j] = T[n8 + j][d];
    *(u16x8*)(vt + (size_t)(bh * 64 + d) * N_ + tile * 64 + n8) = o;
  }
}

// ---------------------------------------------------------------------------
// bf16 MFMA GEMM: C[M,Nn] = A[M,K] @ B[K,Nn].  When OUTBF, columns < 1024 are
// scaled by qscale (folds softmax 1/sqrt(d)*log2e into the Q part of QKV).
// ---------------------------------------------------------------------------
template<bool BIAS, bool OUTBF>
__global__ __launch_bounds__(256, 2)
void gemm_bf16(const u16* __restrict__ A, const u16* __restrict__ Bt,
               const float* __restrict__ bias, float* __restrict__ Cf,
               u16* __restrict__ Cb, int M, int Nn, int K, float qscale)
{
  __shared__ u16 As[128][40];
  __shared__ u16 Bs[128][40];

  const int tid = threadIdx.x;
  const int lane = tid & 63, wv = tid >> 6;
  const int wr = wv >> 1, wc = wv & 1;
  const int lr = lane & 15, lk = (lane >> 4) * 8;

  f32x4 acc[4][4];
#pragma unroll
  for (int m = 0; m < 4; ++m)
#pragma unroll
    for (int n = 0; n < 4; ++n) acc[m][n] = (f32x4){0.f, 0.f, 0.f, 0.f};

  const u16* Ag = A + (size_t)(blockIdx.y * 128) * K;
  const u16* Bg = Bt + (size_t)(blockIdx.x * 128) * K;

  for (int kt = 0; kt < K; kt += 32) {
#pragma unroll
    for (int i = 0; i < 2; ++i) {
      const int f = tid + i * 256;
      const int row = f >> 2, kq = (f & 3) * 8;
      *(u16x8*)&As[row][kq] = *(const u16x8*)(Ag + (size_t)row * K + kt + kq);
      *(u16x8*)&Bs[row][kq] = *(const u16x8*)(Bg + (size_t)row * K + kt + kq);
    }
    __syncthreads();

    bf16x8 a[4], b[4];
#pragma unroll
    for (int m = 0; m < 4; ++m) a[m] = *(bf16x8*)&As[wr * 64 + m * 16 + lr][lk];
#pragma unroll
    for (int n = 0; n < 4; ++n) b[n] = *(bf16x8*)&Bs[wc * 64 + n * 16 + lr][lk];
#pragma unroll
    for (int m = 0; m < 4; ++m)
#pragma unroll
      for (int n = 0; n < 4; ++n)
        acc[m][n] = __builtin_amdgcn_mfma_f32_16x16x32_bf16(a[m], b[n], acc[m][n], 0, 0, 0);
    __syncthreads();
  }

  // C/D layout: col=lane&15, row=(lane>>4)*4+reg   [HW-verified round 3]
#pragma unroll
  for (int n = 0; n < 4; ++n) {
    const int col = blockIdx.x * 128 + wc * 64 + n * 16 + lr;
    const float bv = BIAS ? bias[col] : 0.f;
    const float sc = (OUTBF && col < 1024) ? qscale : 1.0f;
#pragma unroll
    for (int m = 0; m < 4; ++m) {
      const int rbase = blockIdx.y * 128 + wr * 64 + m * 16 + (lane >> 4) * 4;
#pragma unroll
      for (int r = 0; r < 4; ++r) {
        if (OUTBF) Cb[(size_t)(rbase + r) * Nn + col] = f2bf(acc[m][n][r] * sc);
        else       Cf[(size_t)(rbase + r) * Nn + col] = acc[m][n][r] + bv;
      }
    }
  }
}

// ---------------------------------------------------------------------------
// MFMA flash attention, SWAPPED QK^T (S = mfma(K,Q)): lane holds ONE q-row
// (col=l15) x 16 keys (rows lg*4+r over 4 frags) => softmax row-reduce is
// IN-LANE (no ds_bpermute on the common path).  Defer-max: skip iters have
// zero cross-lane ops; rescale iters use 2 shfl_xor (max) + 4 shfl (scf
// broadcast to PV row layout).  l kept as per-lane partial, reduced once in
// the epilogue.  P stored as ds_write_b64 (keys contiguous per lane).
// 8 waves, QBLK=128, KVBLK=64, reg-prefetch dbuf, 1 barrier/iter, XCD swizzle.
// ---------------------------------------------------------------------------
__global__ __launch_bounds__(512, 2)
void attn_mfma(const u16* __restrict__ qkv, const u16* __restrict__ vt,
               u16* __restrict__ att)
{
  __shared__ u16 Ks[2][64][72];
  __shared__ u16 Vs[2][64][72];   // V^T tile: [d][key]
  __shared__ u16 Ps[128][72];     // Q staging, then P [qrow][key]

  const int tid = threadIdx.x;
  const int lane = tid & 63, wv = tid >> 6;     // 8 waves
  const int l15 = lane & 15, lg = lane >> 4;
  const int bid = blockIdx.x;
  const int swz = (bid & 7) * 64 + (bid >> 3);  // 512 % 8 == 0: bijective
  const int bh = swz >> 4, qt = swz & 15;
  const int b = bh >> 4, h = bh & 15;

  const size_t qbase = (size_t)(b * N_ + qt * 128) * 3072 + h * 64;
  const size_t kcol  = (size_t)b * N_ * 3072 + 1024 + h * 64;
  const size_t vbase = (size_t)(bh * 64) * N_;

  // staging: 512 threads cover a 64x64 bf16 tile with one u16x8 each
  const int srow = tid >> 3, sc8 = (tid & 7) * 8;

  // ---- prologue: stage Q (128x64) into Ps and K/V tile 0 into buf 0 ----
  *(u16x8*)&Ps[srow][sc8]      = *(const u16x8*)(qkv + qbase + (size_t)srow * 3072 + sc8);
  *(u16x8*)&Ps[64 + srow][sc8] = *(const u16x8*)(qkv + qbase + (size_t)(64 + srow) * 3072 + sc8);
  *(u16x8*)&Ks[0][srow][sc8]   = *(const u16x8*)(qkv + kcol + (size_t)srow * 3072 + sc8);
  *(u16x8*)&Vs[0][srow][sc8]   = *(const u16x8*)(vt + vbase + (size_t)srow * N_ + sc8);
  __syncthreads();
  bf16x8 qf[2];   // B-operand: col=l15 -> q-row wv*16+l15, k(d)=lg*8
#pragma unroll
  for (int ks = 0; ks < 2; ++ks) qf[ks] = *(bf16x8*)&Ps[wv * 16 + l15][ks * 32 + lg * 8];
  __syncthreads();   // qf reads complete before iter-0 P-stores into Ps

  f32x4 accO[4];
#pragma unroll
  for (int n = 0; n < 4; ++n) accO[n] = (f32x4){0.f, 0.f, 0.f, 0.f};
  float m = -INFINITY;   // running row max for q = wv*16+l15 (consistent over lg)
  float l = 0.f;         // per-lane PARTIAL sum (this lane's 16 keys/iter)

  for (int t = 0; t < N_ / 64; ++t) {
    const int cur = t & 1;

    // ---- issue next tile's global loads (latency hidden under compute) ----
    u16x8 kpre, vpre;
    if (t + 1 < N_ / 64) {
      kpre = *(const u16x8*)(qkv + kcol + (size_t)((t + 1) * 64 + srow) * 3072 + sc8);
      vpre = *(const u16x8*)(vt + vbase + (size_t)srow * N_ + (t + 1) * 64 + sc8);
    }

    // ---- S = K Q^T (swapped): s[n][r] = S[key n*16+lg*4+r][q l15] ----
    f32x4 s[4];
    __builtin_amdgcn_s_setprio(1);
#pragma unroll
    for (int n = 0; n < 4; ++n) {
      s[n] = (f32x4){0.f, 0.f, 0.f, 0.f};
#pragma unroll
      for (int ks = 0; ks < 2; ++ks) {
        const bf16x8 kf = *(bf16x8*)&Ks[cur][n * 16 + l15][ks * 32 + lg * 8];
        s[n] = __builtin_amdgcn_mfma_f32_16x16x32_bf16(kf, qf[ks], s[n], 0, 0, 0);
      }
    }
    __builtin_amdgcn_s_setprio(0);

    // ---- online softmax: IN-LANE over this lane's 16 keys ----
    float mx = s[0][0];
#pragma unroll
    for (int n = 0; n < 4; ++n)
#pragma unroll
      for (int r = 0; r < 4; ++r) mx = fmaxf(mx, s[n][r]);

    const bool skip = __all(mx <= m + 11.0f);   // wave-uniform branch
    if (!skip) {
      // true row max across the 4 lg-groups (lanes sharing l15)
      mx = fmaxf(mx, __shfl_xor(mx, 16));
      mx = fmaxf(mx, __shfl_xor(mx, 32));
      const float mn = fmaxf(m, mx);
      const float scf = exp2f(m - mn);          // rescale for q = l15
      m = mn;
      l *= scf;
      // broadcast scf to PV row layout: accO rows are q = wv*16 + lg*4 + r
      float scr[4];
#pragma unroll
      for (int r = 0; r < 4; ++r) scr[r] = __shfl(scf, lg * 4 + r);
#pragma unroll
      for (int n = 0; n < 4; ++n)
#pragma unroll
        for (int r = 0; r < 4; ++r) accO[n][r] *= scr[r];
    }

    // p = exp2(s - m); accumulate per-lane partial sum; pack to bf16
#pragma unroll
    for (int n = 0; n < 4; ++n) {
      u16x4 po;
#pragma unroll
      for (int r = 0; r < 4; ++r) {
        const float p = exp2f(s[n][r] - m);     // bounded by 2^11 when deferred
        l += p;
        po[r] = f2bf(p);
      }
      // keys n*16+lg*4..+3 are contiguous cols -> single b64 store
      *(u16x4*)&Ps[wv * 16 + l15][n * 16 + lg * 4] = po;
    }

    // ---- O += P V (unchanged layout) ----
    __builtin_amdgcn_s_setprio(1);
#pragma unroll
    for (int ks = 0; ks < 2; ++ks) {
      const bf16x8 pa = *(bf16x8*)&Ps[wv * 16 + l15][ks * 32 + lg * 8];
#pragma unroll
      for (int n = 0; n < 4; ++n) {
        const bf16x8 vf = *(bf16x8*)&Vs[cur][n * 16 + l15][ks * 32 + lg * 8];
        accO[n] = __builtin_amdgcn_mfma_f32_16x16x32_bf16(pa, vf, accO[n], 0, 0, 0);
      }
    }
    __builtin_amdgcn_s_setprio(0);

    // ---- write prefetched tile into alternate buffer ----
    // Safe with ONE barrier/iter: last readers of buf[cur^1] ran in iter t-1,
    // separated from these writes by iter t-1's barrier.
    if (t + 1 < N_ / 64) {
      *(u16x8*)&Ks[cur ^ 1][srow][sc8] = kpre;
      *(u16x8*)&Vs[cur ^ 1][srow][sc8] = vpre;
    }
    __syncthreads();
  }

  // ---- epilogue: total l per q-row (2 shfl), redistribute, store ----
  float lt = l + __shfl_xor(l, 16);
  lt += __shfl_xor(lt, 32);                     // total for q = wv*16 + l15
  const float linv = 1.f / lt;
  float inv[4];
#pragma unroll
  for (int r = 0; r < 4; ++r) inv[r] = __shfl(linv, lg * 4 + r);
#pragma unroll
  for (int n = 0; n < 4; ++n) {
    const int col = h * 64 + n * 16 + l15;
#pragma unroll
    for (int r = 0; r < 4; ++r) {
      const int row = b * N_ + qt * 128 + wv * 16 + lg * 4 + r;
      att[(size_t)row * C_ + col] = f2bf(accO[n][r] * inv[r]);
    }
  }
}

// ---------------------------------------------------------------------------
extern "C" void kernel_launch(void* const* d_in, const int* in_sizes, int n_in,
                              void* d_out, int out_size, void* d_ws, size_t ws_size,
                              hipStream_t stream) {
  const float* x      = (const float*)d_in[0];   // [B, N, C]
  const float* w_qkv  = (const float*)d_in[1];   // [C, 3C]
  const float* w_proj = (const float*)d_in[2];   // [C, C]
  const float* b_proj = (const float*)d_in[3];   // [C]
  float* out = (float*)d_out;                    // [B, N, C] fp32

  // ws layout (48 MB, all bf16).  vt ALIASES xb (xb dead after gemm1).
  u16* qkvb = (u16*)d_ws;                        // [4096][3072]  (Q part pre-scaled)
  u16* xb   = qkvb + (size_t)4096 * 3072;        // [4096][1024]  (later: vt)
  u16* wqt  = xb   + (size_t)4096 * 1024;        // [3072][1024] = w_qkv^T
  u16* wpt  = wqt  + (size_t)3072 * 1024;        // [1024][1024] = w_proj^T
  u16* aob  = wpt  + (size_t)1024 * 1024;        // [4096][1024]
  u16* vt   = xb;                                // [32*64][2048] = V^T per (b,h)

  const int M = B_ * N_;  // 4096

  cvt_f32_bf16<<<4096, 256, 0, stream>>>(x, xb);
  tcvt_bf16<<<dim3(96, 32), 256, 0, stream>>>(w_qkv, wqt, C_, 3 * C_);
  tcvt_bf16<<<dim3(32, 32), 256, 0, stream>>>(w_proj, wpt, C_, C_);

  // 1) QKV projection -> bf16 qkv [B,N,3,H,D], Q columns pre-scaled
  gemm_bf16<false, true><<<dim3(3 * C_ / 128, M / 128), 256, 0, stream>>>(
      xb, wqt, nullptr, nullptr, qkvb, M, 3 * C_, C_, QSCALE);

  // 1b) V^T extraction (overwrites xb region — xb is dead now)
  vtrans<<<dim3(32, 32), 256, 0, stream>>>(qkvb, vt);

  // 2) MFMA flash attention (swapped QK^T, in-lane softmax)
  attn_mfma<<<dim3(N_ / 128 * B_ * H_), 512, 0, stream>>>(qkvb, vt, aob);

  // 3) output projection + bias -> fp32 d_out
  gemm_bf16<true, false><<<dim3(C_ / 128, M / 128), 256, 0, stream>>>(
      aob, wpt, b_proj, out, nullptr, M, C_, C_, 1.0f);
}